// Round 8
// baseline (248.741 us; speedup 1.0000x reference)
//
#include <hip/hip_runtime.h>
#include <hip/hip_bf16.h>

// GPT-2 attention: B=2, S=2048, D=1024, H=16, HS=64
// cvt(x)->bf16 ; fused weight transposes -> [N][K] bf16 ; GEMM1 (QKV proj, Q scaled by
// 0.125*log2e, V via LDS-transpose epilogue) ; flash attention (8-wave blocks, adjacent
// q-tile groups, 34 balanced rounds, swapped-QK^T in-register softmax, cvt_pk P-pack,
// dbuf KV, swizzled LDS, exp2 softmax, defer-max) ; GEMM2 (+bias, fp32).

#define Bb 2
#define Ss 2048
#define Dd 1024
#define Hh 16
#define HSs 64

typedef __bf16 bf16x8 __attribute__((ext_vector_type(8)));
typedef float  f32x4  __attribute__((ext_vector_type(4)));

__device__ __forceinline__ unsigned short f2bf(float f) {
  unsigned int u = __float_as_uint(f);
  unsigned int lsb = (u >> 16) & 1u;
  u += 0x7fffu + lsb;               // round-to-nearest-even (finite values)
  return (unsigned short)(u >> 16);
}

__device__ __forceinline__ unsigned int cvtpk(float lo, float hi) {
  unsigned int r;
  asm("v_cvt_pk_bf16_f32 %0, %1, %2" : "=v"(r) : "v"(lo), "v"(hi));
  return r;
}

__device__ __forceinline__ void async16(const unsigned short* g, unsigned short* l) {
  __builtin_amdgcn_global_load_lds(
      (const __attribute__((address_space(1))) unsigned int*)g,
      (__attribute__((address_space(3))) unsigned int*)l,
      16, 0, 0);
}

// ---------------------------------------------------------------- cvt x -> bf16
__global__ __launch_bounds__(256) void k_cvt_bf16(const float* __restrict__ in,
                                                  unsigned short* __restrict__ out,
                                                  int n) {
  int i = (blockIdx.x * 256 + threadIdx.x) * 4;
  int stride = gridDim.x * 256 * 4;
  for (; i < n; i += stride) {
    float4 v = *reinterpret_cast<const float4*>(in + i);
    ushort4 o;
    o.x = f2bf(v.x); o.y = f2bf(v.y); o.z = f2bf(v.z); o.w = f2bf(v.w);
    *reinterpret_cast<ushort4*>(out + i) = o;
  }
}

// --------------------------------------- fused transposes: w_qkv and w_proj -> [N][K] bf16
__global__ __launch_bounds__(256) void k_transpose2(const float* __restrict__ wqkv,
                                                    unsigned short* __restrict__ wqkvT,
                                                    const float* __restrict__ wproj,
                                                    unsigned short* __restrict__ wprojT) {
  __shared__ float t[32][33];
  int bx = blockIdx.x;
  const float* in; unsigned short* out; int R = 1024, C;
  if (bx < 96) { in = wqkv; out = wqkvT; C = 3072; }
  else         { in = wproj; out = wprojT; C = 1024; bx -= 96; }
  int c0 = bx * 32, r0 = blockIdx.y * 32;
  int tx = threadIdx.x, ty = threadIdx.y;  // block (32,8)
  #pragma unroll
  for (int i = 0; i < 32; i += 8)
    t[ty + i][tx] = in[(size_t)(r0 + ty + i) * C + (c0 + tx)];
  __syncthreads();
  #pragma unroll
  for (int i = 0; i < 32; i += 8)
    out[(size_t)(c0 + ty + i) * R + (r0 + tx)] = f2bf(t[tx][ty + i]);
}

// ---------------------------------------------------------------- GEMM1: QKV proj
// single-buffer 32KB; V blocks (n0>=2048) use LDS-transpose epilogue for coalesced Vt writes
__global__ __launch_bounds__(256) void k_gemm_qkv(const unsigned short* __restrict__ A,
                                                  const unsigned short* __restrict__ Bt,
                                                  const float* __restrict__ bias,
                                                  unsigned short* __restrict__ Qg,
                                                  unsigned short* __restrict__ Kg,
                                                  unsigned short* __restrict__ Vt) {
  __shared__ unsigned short S[2][128 * 64];   // S[0]=As, S[1]=Bs; reused as 128x128 Ts
  const int K = 1024;
  int bid = blockIdx.x;
  int swz = (bid % 8) * 96 + bid / 8;         // XCD-contiguous
  int tm = swz / 24, tn = swz % 24;
  int m0 = tm * 128, n0 = tn * 128;
  int tid = threadIdx.x;
  int w = tid >> 6, l = tid & 63;
  int lr = l & 15, lg = l >> 4;
  int wm = (w >> 1) * 64, wn = (w & 1) * 64;
  int srow = l >> 3, scol = (l & 7) * 8;

  f32x4 acc[4][4];
  #pragma unroll
  for (int i = 0; i < 4; ++i)
    #pragma unroll
    for (int j = 0; j < 4; ++j)
      acc[i][j] = (f32x4){0.f, 0.f, 0.f, 0.f};

  for (int k0 = 0; k0 < K; k0 += 64) {
    #pragma unroll
    for (int c = 0; c < 4; ++c) {
      int chunk = w * 4 + c;
      int row = chunk * 8 + srow;
      async16(&A[(size_t)(m0 + row) * K + k0 + scol], &S[0][chunk * 512]);
      async16(&Bt[(size_t)(n0 + row) * K + k0 + scol], &S[1][chunk * 512]);
    }
    __syncthreads();
    #pragma unroll
    for (int kk = 0; kk < 64; kk += 32) {
      bf16x8 af[4], bfr[4];
      #pragma unroll
      for (int mf = 0; mf < 4; ++mf)
        af[mf] = *reinterpret_cast<const bf16x8*>(&S[0][(wm + mf * 16 + lr) * 64 + kk + lg * 8]);
      #pragma unroll
      for (int nf = 0; nf < 4; ++nf)
        bfr[nf] = *reinterpret_cast<const bf16x8*>(&S[1][(wn + nf * 16 + lr) * 64 + kk + lg * 8]);
      #pragma unroll
      for (int mf = 0; mf < 4; ++mf)
        #pragma unroll
        for (int nf = 0; nf < 4; ++nf)
          acc[mf][nf] = __builtin_amdgcn_mfma_f32_16x16x32_bf16(af[mf], bfr[nf], acc[mf][nf], 0, 0, 0);
    }
    __syncthreads();
  }

  if (n0 < 2048) {
    #pragma unroll
    for (int mf = 0; mf < 4; ++mf) {
      #pragma unroll
      for (int nf = 0; nf < 4; ++nf) {
        int n = n0 + wn + nf * 16 + lr;
        int t = n >> 10, r = n & 1023;
        int h = r >> 6, cc = r & 63;
        float bv = bias[n];
        #pragma unroll
        for (int j = 0; j < 4; ++j) {
          int m = m0 + wm + mf * 16 + lg * 4 + j;
          int b = m >> 11, s = m & 2047;
          size_t idx = ((size_t)(b * Hh + h) * Ss + s) * HSs + cc;
          float v = acc[mf][nf][j] + bv;
          // Q pre-scaled by (1/8)*log2(e): attention softmax runs in exp2 domain
          if (t == 0) Qg[idx] = f2bf(v * 0.1803368801111244f);
          else        Kg[idx] = f2bf(v);
        }
      }
    }
  } else {
    // V: transpose 128x128 tile in LDS, write coalesced rows along s
    unsigned short* Ts = &S[0][0];            // [128 n][128 m], XOR-swizzled
    #pragma unroll
    for (int mf = 0; mf < 4; ++mf)
      #pragma unroll
      for (int nf = 0; nf < 4; ++nf) {
        int nl = wn + nf * 16 + lr;
        float bv = bias[n0 + nl];
        #pragma unroll
        for (int j = 0; j < 4; ++j) {
          int ml = wm + mf * 16 + lg * 4 + j;
          Ts[nl * 128 + (ml ^ ((nl & 7) << 3))] = f2bf(acc[mf][nf][j] + bv);
        }
      }
    __syncthreads();
    int nl = tid >> 1, mh = (tid & 1) * 64;
    int n = n0 + nl;
    int h = (n & 1023) >> 6, cc = n & 63;
    int bb = m0 >> 11, s0 = m0 & 2047;
    unsigned short* dst = &Vt[((size_t)(bb * Hh + h) * HSs + cc) * Ss + s0];
    #pragma unroll
    for (int i = 0; i < 8; ++i) {
      int m = mh + i * 8;
      bf16x8 v = *reinterpret_cast<const bf16x8*>(&Ts[nl * 128 + (m ^ ((nl & 7) << 3))]);
      *reinterpret_cast<bf16x8*>(&dst[m]) = v;
    }
  }
}

// ---------------------------------------------------------------- flash attention
// grid 512: bid = p*32 + bh (bh low bits -> XCD-pinned). 8 waves; group g = w>>2.
// Phase A: group g owns q-tile 2p+g ; Phase B: q-tile 30-2p+g. Rounds = (2p+2)+(32-2p)=34.
// Swapped QK^T (mfma(K,Q)) -> lane holds P-row q=lr fully in-register: softmax = in-reg
// reduce + 2 shfls. KVBLK=64 double-buffered, barrier-at-top, XOR-swizzled LDS.
__global__ __launch_bounds__(512, 4) void k_attn(const unsigned short* __restrict__ Qg,
                                                 const unsigned short* __restrict__ Kg,
                                                 const unsigned short* __restrict__ Vt,
                                                 unsigned short* __restrict__ Ob) {
  __shared__ unsigned short Ks[2][64 * 64];   // 16 KB
  __shared__ unsigned short Vs[2][64 * 64];   // 16 KB
  __shared__ unsigned short Ps[8][16 * 64];   // 16 KB (per-wave P, swizzled)

  int bid = blockIdx.x;
  int p = bid >> 5, bh = bid & 31;
  int b = bh >> 4, h = bh & 15;

  int tid = threadIdx.x;
  int w = tid >> 6, l = tid & 63;
  int g = w >> 2;
  int lr = l & 15, lg = l >> 4;
  int lg4 = lg * 4;
  int srow = l >> 3, scol = (l & 7) * 8;
  int swcol = scol ^ (srow << 3);             // pre-swizzled global source column

  int qtA = 2 * p + g;
  int qtB = 30 - 2 * p + g;
  int ntA = 2 * p + 2;                        // phase-A rounds; total rounds = 34

  const size_t kbase = (size_t)bh * Ss;
  const size_t vbase = (size_t)bh * HSs;

  int qt = qtA;
  int qw0 = qtA * 64 + (w & 3) * 16;          // wave's 16-q-row base
  bf16x8 qf[2];
  #pragma unroll
  for (int kx = 0; kx < 2; ++kx)
    qf[kx] = *reinterpret_cast<const bf16x8*>(
        &Qg[(kbase + qw0 + lr) * HSs + kx * 32 + lg * 8]);

  f32x4 oacc[4];
  #pragma unroll
  for (int nf = 0; nf < 4; ++nf) oacc[nf] = (f32x4){0.f, 0.f, 0.f, 0.f};
  float mrun = -1e30f, lrun = 0.f;            // stats for q = qw0 + lr (home lane)

  auto stage = [&](int tile, int buf) {       // wave w stages chunk w of K and V (1KB each)
    int rr = w * 8 + srow;
    async16(&Kg[(kbase + tile * 64 + rr) * HSs + swcol], &Ks[buf][w * 512]);
    async16(&Vt[(vbase + rr) * Ss + tile * 64 + swcol], &Vs[buf][w * 512]);
  };

  auto writeO = [&]() {
    float rinv = 1.0f / lrun;
    float rj[4];
    #pragma unroll
    for (int j = 0; j < 4; ++j) rj[j] = __shfl(rinv, lg4 + j);
    #pragma unroll
    for (int j = 0; j < 4; ++j) {
      int s = qw0 + lg4 + j;
      #pragma unroll
      for (int nf = 0; nf < 4; ++nf) {
        int cc = nf * 16 + lr;
        Ob[((size_t)(b * Ss + s)) * Dd + h * HSs + cc] = f2bf(oacc[nf][j] * rj[j]);
      }
    }
  };

  stage(0, 0);

  for (int gi = 0; gi < 34; ++gi) {
    __syncthreads();          // drains previous prefetch (its latency hid under compute)

    if (gi + 1 < 34) {
      int nt = gi + 1;
      int tile = (nt < ntA) ? nt : (nt - ntA);
      stage(tile, nt & 1);
    }

    if (gi == ntA) {                           // phase switch A -> B
      writeO();
      qt = qtB; qw0 = qtB * 64 + (w & 3) * 16;
      #pragma unroll
      for (int kx = 0; kx < 2; ++kx)
        qf[kx] = *reinterpret_cast<const bf16x8*>(
            &Qg[(kbase + qw0 + lr) * HSs + kx * 32 + lg * 8]);
      #pragma unroll
      for (int nf = 0; nf < 4; ++nf) oacc[nf] = (f32x4){0.f, 0.f, 0.f, 0.f};
      mrun = -1e30f; lrun = 0.f;
    }

    int t = (gi < ntA) ? gi : gi - ntA;
    int cur = gi & 1;

    if (t <= qt) {
      // QK^T swapped: sacc[nf][j] = S[q=qw0+lr][k = t*64 + nf*16 + lg4 + j]
      f32x4 sacc[4];
      #pragma unroll
      for (int nf = 0; nf < 4; ++nf) sacc[nf] = (f32x4){0.f, 0.f, 0.f, 0.f};
      #pragma unroll
      for (int kx = 0; kx < 2; ++kx) {
        bf16x8 kf[4];
        #pragma unroll
        for (int nf = 0; nf < 4; ++nf)
          kf[nf] = *reinterpret_cast<const bf16x8*>(
              &Ks[cur][(nf * 16 + lr) * 64 + ((kx * 32 + lg * 8) ^ ((lr & 7) << 3))]);
        #pragma unroll
        for (int nf = 0; nf < 4; ++nf)
          sacc[nf] = __builtin_amdgcn_mfma_f32_16x16x32_bf16(kf[nf], qf[kx], sacc[nf], 0, 0, 0);
      }

      if (t == qt) {                           // diagonal tile: causal mask
        int qg2 = qw0 + lr;
        #pragma unroll
        for (int nf = 0; nf < 4; ++nf)
          #pragma unroll
          for (int j = 0; j < 4; ++j) {
            int kg = t * 64 + nf * 16 + lg4 + j;
            if (kg > qg2) sacc[nf][j] = -1e30f;
          }
      }

      // row stats fully in-register (row = q = lr), cross-lane only over lg (2 shfls)
      float rm = -1e30f;
      #pragma unroll
      for (int nf = 0; nf < 4; ++nf)
        rm = fmaxf(rm, fmaxf(fmaxf(sacc[nf][0], sacc[nf][1]),
                             fmaxf(sacc[nf][2], sacc[nf][3])));
      rm = fmaxf(rm, __shfl_xor(rm, 16));
      rm = fmaxf(rm, __shfl_xor(rm, 32));

      if (__any(rm > mrun + 8.f)) {            // defer-max rescale
        float mnew = fmaxf(mrun, rm);
        float cf = exp2f(mrun - mnew);
        mrun = mnew; lrun *= cf;
        float cj[4];
        #pragma unroll
        for (int j = 0; j < 4; ++j) cj[j] = __shfl(cf, lg4 + j);
        #pragma unroll
        for (int nf = 0; nf < 4; ++nf)
          #pragma unroll
          for (int j = 0; j < 4; ++j)
            oacc[nf][j] *= cj[j];
      }

      float psum = 0.f;
      #pragma unroll
      for (int nf = 0; nf < 4; ++nf)
        #pragma unroll
        for (int j = 0; j < 4; ++j) {
          float pv = exp2f(sacc[nf][j] - mrun);
          sacc[nf][j] = pv;
          psum += pv;
        }
      psum += __shfl_xor(psum, 16);
      psum += __shfl_xor(psum, 32);
      lrun += psum;

      // P pack (cvt_pk) -> LDS b64 writes: P[q=lr][k], swizzled
      #pragma unroll
      for (int nf = 0; nf < 4; ++nf) {
        uint2 pk;
        pk.x = cvtpk(sacc[nf][0], sacc[nf][1]);
        pk.y = cvtpk(sacc[nf][2], sacc[nf][3]);
        int col = nf * 16 + lg4;
        *reinterpret_cast<uint2*>(&Ps[w][lr * 64 + (col ^ ((lr & 7) << 3))]) = pk;
      }

      // PV
      #pragma unroll
      for (int kx = 0; kx < 2; ++kx) {
        bf16x8 pf = *reinterpret_cast<const bf16x8*>(
            &Ps[w][lr * 64 + ((kx * 32 + lg * 8) ^ ((lr & 7) << 3))]);
        bf16x8 vf[4];
        #pragma unroll
        for (int nf = 0; nf < 4; ++nf)
          vf[nf] = *reinterpret_cast<const bf16x8*>(
              &Vs[cur][(nf * 16 + lr) * 64 + ((kx * 32 + lg * 8) ^ ((lr & 7) << 3))]);
        #pragma unroll
        for (int nf = 0; nf < 4; ++nf)
          oacc[nf] = __builtin_amdgcn_mfma_f32_16x16x32_bf16(pf, vf[nf], oacc[nf], 0, 0, 0);
      }
    }
  }

  writeO();
}

// ---------------------------------------------------------------- GEMM2: out proj (single-buffer)
__global__ __launch_bounds__(256) void k_gemm_out(const unsigned short* __restrict__ A,
                                                  const unsigned short* __restrict__ Bt,
                                                  const float* __restrict__ bias,
                                                  float* __restrict__ Out) {
  __shared__ unsigned short As[128 * 64];
  __shared__ unsigned short Bs[128 * 64];
  const int K = 1024;
  int bid = blockIdx.x;
  int swz = (bid % 8) * 32 + bid / 8;       // XCD-contiguous
  int tm = swz / 8, tn = swz % 8;
  int m0 = tm * 128, n0 = tn * 128;
  int tid = threadIdx.x;
  int w = tid >> 6, l = tid & 63;
  int lr = l & 15, lg = l >> 4;
  int wm = (w >> 1) * 64, wn = (w & 1) * 64;
  int srow = l >> 3, scol = (l & 7) * 8;

  f32x4 acc[4][4];
  #pragma unroll
  for (int i = 0; i < 4; ++i)
    #pragma unroll
    for (int j = 0; j < 4; ++j)
      acc[i][j] = (f32x4){0.f, 0.f, 0.f, 0.f};

  for (int k0 = 0; k0 < K; k0 += 64) {
    #pragma unroll
    for (int c = 0; c < 4; ++c) {
      int chunk = w * 4 + c;
      int row = chunk * 8 + srow;
      async16(&A[(size_t)(m0 + row) * K + k0 + scol], &As[chunk * 512]);
      async16(&Bt[(size_t)(n0 + row) * K + k0 + scol], &Bs[chunk * 512]);
    }
    __syncthreads();
    #pragma unroll
    for (int kk = 0; kk < 64; kk += 32) {
      bf16x8 af[4], bfr[4];
      #pragma unroll
      for (int mf = 0; mf < 4; ++mf)
        af[mf] = *reinterpret_cast<const bf16x8*>(&As[(wm + mf * 16 + lr) * 64 + kk + lg * 8]);
      #pragma unroll
      for (int nf = 0; nf < 4; ++nf)
        bfr[nf] = *reinterpret_cast<const bf16x8*>(&Bs[(wn + nf * 16 + lr) * 64 + kk + lg * 8]);
      #pragma unroll
      for (int mf = 0; mf < 4; ++mf)
        #pragma unroll
        for (int nf = 0; nf < 4; ++nf)
          acc[mf][nf] = __builtin_amdgcn_mfma_f32_16x16x32_bf16(af[mf], bfr[nf], acc[mf][nf], 0, 0, 0);
    }
    __syncthreads();
  }

  #pragma unroll
  for (int mf = 0; mf < 4; ++mf)
    #pragma unroll
    for (int nf = 0; nf < 4; ++nf) {
      int n = n0 + wn + nf * 16 + lr;
      float bv = bias[n];
      #pragma unroll
      for (int j = 0; j < 4; ++j) {
        int m = m0 + wm + mf * 16 + lg * 4 + j;
        Out[(size_t)m * 1024 + n] = acc[mf][nf][j] + bv;
      }
    }
}

// ---------------------------------------------------------------- launch
extern "C" void kernel_launch(void* const* d_in, const int* in_sizes, int n_in,
                              void* d_out, int out_size, void* d_ws, size_t ws_size,
                              hipStream_t stream) {
  (void)in_sizes; (void)n_in; (void)out_size; (void)ws_size;
  const float* x      = (const float*)d_in[0];
  const float* w_qkv  = (const float*)d_in[2];
  const float* b_qkv  = (const float*)d_in[3];
  const float* w_proj = (const float*)d_in[4];
  const float* b_proj = (const float*)d_in[5];
  float* out = (float*)d_out;

  char* ws = (char*)d_ws;
  unsigned short* xb    = (unsigned short*)(ws);              //  8 MB [4096][1024]
  unsigned short* wqkvT = (unsigned short*)(ws + 8388608);    //  6 MB [3072][1024]
  unsigned short* wpT   = (unsigned short*)(ws + 14680064);   //  2 MB [1024][1024]
  unsigned short* Qg    = (unsigned short*)(ws + 16777216);   //  8 MB [32][2048][64]
  unsigned short* Kg    = (unsigned short*)(ws + 25165824);   //  8 MB [32][2048][64]
  unsigned short* Vt    = (unsigned short*)(ws + 33554432);   //  8 MB [32][64][2048]
  unsigned short* attnb = (unsigned short*)(ws + 41943040);   //  8 MB [4096][1024]

  k_cvt_bf16<<<dim3(2048), dim3(256), 0, stream>>>(x, xb, Bb * Ss * Dd);
  k_transpose2<<<dim3(128, 32), dim3(32, 8), 0, stream>>>(w_qkv, wqkvT, w_proj, wpT);
  k_gemm_qkv<<<dim3(32 * 24), dim3(256), 0, stream>>>(xb, wqkvT, b_qkv, Qg, Kg, Vt);
  k_attn<<<dim3(512), dim3(512), 0, stream>>>(Qg, Kg, Vt, attnb);
  k_gemm_out<<<dim3(32 * 8), dim3(256), 0, stream>>>(attnb, wpT, b_proj, out);
}